// Round 7
// baseline (199.722 us; speedup 1.0000x reference)
//
#include <hip/hip_runtime.h>
#include <hip/hip_bf16.h>

#define NN 8192
#define DD 128

typedef short short8 __attribute__((ext_vector_type(8)));
typedef __bf16 bf16x8 __attribute__((ext_vector_type(8)));
typedef float f32x4 __attribute__((ext_vector_type(4)));

// unit-norm simplification (x2=y2=1):
//   d = 1 + c^2 - 2cs ;  q = nd^2 = 2c(1-s)/d ;  1-q = (1-c)^2/d exactly
//   rr = (1+nd)/(1-nd) = (1+nd)^2 * d/(1-c)^2
//   adc = -dist/T = KL*log2(rr) ; e = exp(adc) = exp2(KE*log2(rr))
#define MKc (-0.110803324099723f)   // -2c/(1-c)^2
#define PKc (0.110803324099723f)    // +2c/(1-c)^2
#define C1Kc (1.110803324099723f)   // (1+c^2)/(1-c)^2
#define KEc (-8.944271909999159f)   // -1/(sqrt_c*T)
#define KLc (-6.199696797323639f)   // KE*ln2

// ---------------- prep: normalize 16 rows/block -> bf16, + label histogram ----------------
__global__ __launch_bounds__(256) void prep_kernel(const float* __restrict__ x,
                                                   const int* __restrict__ plab,
                                                   const int* __restrict__ slab,
                                                   __hip_bfloat16* __restrict__ fb,
                                                   int* __restrict__ ghist) {
  int r = threadIdx.x >> 4, sub = threadIdx.x & 15;
  int row = blockIdx.x * 16 + r;
  const float4 a = *(const float4*)(x + (size_t)row * DD + sub * 8);
  const float4 b = *(const float4*)(x + (size_t)row * DD + sub * 8 + 4);
  float ss = a.x * a.x + a.y * a.y + a.z * a.z + a.w * a.w +
             b.x * b.x + b.y * b.y + b.z * b.z + b.w * b.w;
  for (int off = 1; off < 16; off <<= 1) ss += __shfl_xor(ss, off, 16);
  float inv = 1.0f / fmaxf(sqrtf(ss), 1e-12f);
  float va[8] = {a.x, a.y, a.z, a.w, b.x, b.y, b.z, b.w};
  short8 h;
  for (int j = 0; j < 8; j++) {
    __hip_bfloat16 t = __float2bfloat16(va[j] * inv);
    h[j] = __builtin_bit_cast(short, t);
  }
  *(short8*)((short*)fb + (size_t)row * DD + sub * 8) = h;
  if (sub == 0) atomicAdd(&ghist[plab[row] * 16 + slab[row]], 1);
}

// ---------------- fused triangular: 128 rows x 256 cols per block ----------------
// unit u in [0,528) enumerates strip pairs (I,J), I<=J, strips of 256 rows.
// block = (u, half): rows [I*256 + half*128, +128) x cols [J*256, +256).
// Row-side: totg/tposg[row] += sums over cols.   Col-side (I<J only):
// totg/tposg[col] += sums over rows (symmetry s_ij = s_ji, mask symmetric).
__global__ __launch_bounds__(256, 4) void fused_tri(
    const __hip_bfloat16* __restrict__ fbg,
    const int* __restrict__ plab, const int* __restrict__ slab,
    float* __restrict__ totg, float* __restrict__ tposg) {
  __shared__ short Bbuf[64 * 128];    // 16 KB, XOR-swizzled B tile
  __shared__ int plc[256], slc[256];  // 2 KB

  const int tid = threadIdx.x;
  const int w = tid >> 6;
  const int lane = tid & 63;
  const int lrow = lane & 15;
  const int quad = lane >> 4;

  // decode triangular unit (uniform scalar)
  const int unit = blockIdx.x >> 1;
  const int half = blockIdx.x & 1;
  int I = 0, rem = unit;
  while (rem >= 32 - I) { rem -= 32 - I; I++; }
  const int J = I + rem;
  const bool isDiag = (I == J);
  const int R0 = I * 256 + half * 128;
  const int C0 = J * 256;

  plc[tid] = plab[C0 + tid];
  slc[tid] = slab[C0 + tid];

  // A fragments + row constants (wave w owns rows R0 + w*32 .. +31, 2 strips of 16)
  bf16x8 af[2][4];
  int plr[2][4], slr[2][4], rowg[2][4];
  for (int strip = 0; strip < 2; strip++) {
    const short* fa = (const short*)fbg + (size_t)(R0 + w * 32 + strip * 16 + lrow) * DD;
    for (int kk = 0; kk < 4; kk++)
      af[strip][kk] = __builtin_bit_cast(bf16x8, *(const short8*)(fa + kk * 32 + quad * 8));
    for (int r = 0; r < 4; r++) {
      int rg = R0 + w * 32 + strip * 16 + quad * 4 + r;
      rowg[strip][r] = rg;
      plr[strip][r] = plab[rg];
      slr[strip][r] = slab[rg];
    }
  }

  float tot[2][4], lgs[2][4];
  for (int s_ = 0; s_ < 2; s_++)
    for (int r = 0; r < 4; r++) { tot[s_][r] = 0.f; lgs[s_][r] = 0.f; }

  for (int tile = 0; tile < 4; tile++) {
    const int CT = C0 + tile * 64;
    __syncthreads();  // previous tile's readers done before overwriting Bbuf
    {
      const short* gb = (const short*)fbg + (size_t)CT * DD;
      for (int i = 0; i < 4; i++) {
        int o = tid + i * 256;  // row-major 16B-unit index
        int row = o >> 4, uu = o & 15;
        int u = (row << 4) + (uu ^ (row & 15));
        *(short8*)(Bbuf + u * 8) = *(const short8*)(gb + o * 8);
      }
    }
    __syncthreads();

    const int lb = tile * 64;
    for (int ct = 0; ct < 4; ct++) {
      const int rt = ct * 16 + lrow;
      bf16x8 bf[4];
      for (int kk = 0; kk < 4; kk++) {
        int u = (rt << 4) + ((kk * 4 + quad) ^ lrow);
        bf[kk] = __builtin_bit_cast(bf16x8, *(const short8*)(Bbuf + u * 8));
      }
      f32x4 acc[2];
      for (int strip = 0; strip < 2; strip++) {
        f32x4 a0 = {0.f, 0.f, 0.f, 0.f};
        for (int kk = 0; kk < 4; kk++)
          a0 = __builtin_amdgcn_mfma_f32_16x16x32_bf16(af[strip][kk], bf[kk], a0, 0, 0, 0);
        acc[strip] = a0;
      }
      const int colg = CT + rt;
      const int pc = plc[lb + rt];
      const int sc = slc[lb + rt];
      float cTot = 0.f, cLg = 0.f;
      for (int strip = 0; strip < 2; strip++) {
        for (int r = 0; r < 4; r++) {
          float s = acc[strip][r];
          float tK = fmaxf(fmaf(s, MKc, PKc), 0.0f);  // 2cK*(1-s), clamped (diag noise)
          float dk = fmaf(s, MKc, C1Kc);              // d*K
          float m = fmaxf(tK * dk, 1e-30f);
          float nd = tK * __builtin_amdgcn_rsqf(m);   // sqrt(tK/dk), 0-safe
          float p1 = 1.0f + nd;
          float rr = p1 * p1 * dk;
          float lg = __log2f(rr);
          float e = exp2f(KEc * lg);
          bool offd = (colg != rowg[strip][r]);
          bool same = (pc == plr[strip][r]) || (sc == slr[strip][r]);
          tot[strip][r] += offd ? e : 0.0f;
          lgs[strip][r] += (same && offd) ? lg : 0.0f;
          cTot += e;                    // col-side credit (used only when !isDiag)
          cLg += same ? lg : 0.0f;
        }
      }
      if (!isDiag) {
        // reduce col credit across the 4 quads (rows), then 16-lane-wide atomic
        cTot += __shfl_xor(cTot, 16, 64);
        cTot += __shfl_xor(cTot, 32, 64);
        cLg += __shfl_xor(cLg, 16, 64);
        cLg += __shfl_xor(cLg, 32, 64);
        if (quad == 0) {
          atomicAdd(&totg[colg], cTot);
          atomicAdd(&tposg[colg], cLg);
        }
      }
    }
  }

  // row-side: reduce across the 16 lanes sharing each output row, then atomics
  for (int strip = 0; strip < 2; strip++) {
    for (int r = 0; r < 4; r++) {
      float t = tot[strip][r], g = lgs[strip][r];
      for (int off = 1; off < 16; off <<= 1) {
        t += __shfl_xor(t, off, 16);
        g += __shfl_xor(g, off, 16);
      }
      if (lrow == 0) {
        atomicAdd(&totg[rowg[strip][r]], t);
        atomicAdd(&tposg[rowg[strip][r]], g);
      }
    }
  }
}

// ---------------- finalize: one block — num_pos analytic, per-row loss, reduce ----------------
__global__ __launch_bounds__(1024) void final_k(const float* __restrict__ totg,
                                                const float* __restrict__ tposg,
                                                const int* __restrict__ plab,
                                                const int* __restrict__ slab,
                                                const int* __restrict__ ghist,
                                                float* __restrict__ out) {
  __shared__ int hist[512];
  __shared__ int cntP[32], cntS[16];
  __shared__ float redP[16], redV[16];
  const int tid = threadIdx.x;
  if (tid < 512) hist[tid] = ghist[tid];
  __syncthreads();
  if (tid < 32) {
    int s = 0;
    for (int j = 0; j < 16; j++) s += hist[tid * 16 + j];
    cntP[tid] = s;
  } else if (tid >= 64 && tid < 80) {
    int s = 0;
    for (int j = 0; j < 32; j++) s += hist[j * 16 + (tid - 64)];
    cntS[tid - 64] = s;
  }
  __syncthreads();
  float accP = 0.f, accV = 0.f;
  for (int i = tid; i < NN; i += 1024) {
    int pl = plab[i], sl = slab[i];
    int np = cntP[pl] + cntS[sl] - hist[pl * 16 + sl] - 1;
    if (np > 0) {
      accP += (KLc * tposg[i]) / (float)np - __logf(totg[i] + 1e-8f);
      accV += 1.f;
    }
  }
  for (int off = 32; off; off >>= 1) {
    accP += __shfl_xor(accP, off, 64);
    accV += __shfl_xor(accV, off, 64);
  }
  int wv = tid >> 6;
  if ((tid & 63) == 0) { redP[wv] = accP; redV[wv] = accV; }
  __syncthreads();
  if (tid == 0) {
    float sp = 0.f, sv = 0.f;
    for (int j = 0; j < 16; j++) { sp += redP[j]; sv += redV[j]; }
    float loss = -(sp / fmaxf(sv, 1.0f)) * 0.5f;  // * TEMPERATURE
    if (sv <= 0.0f || !__builtin_isfinite(loss)) loss = 0.0f;
    out[0] = loss;
  }
}

extern "C" void kernel_launch(void* const* d_in, const int* in_sizes, int n_in,
                              void* d_out, int out_size, void* d_ws, size_t ws_size,
                              hipStream_t stream) {
  const float* x = (const float*)d_in[0];
  const int* pl = (const int*)d_in[1];
  const int* sl = (const int*)d_in[2];
  char* ws = (char*)d_ws;
  __hip_bfloat16* fb = (__hip_bfloat16*)ws;    // 2,097,152 B
  float* totg = (float*)(ws + 2097152);        // 32 KB
  float* tposg = (float*)(ws + 2129920);       // 32 KB
  int* ghist = (int*)(ws + 2162688);           // 2 KB

  (void)hipMemsetAsync(totg, 0, 67584, stream);  // totg, tposg, ghist

  prep_kernel<<<NN / 16, 256, 0, stream>>>(x, pl, sl, fb, ghist);
  fused_tri<<<1056, 256, 0, stream>>>(fb, pl, sl, totg, tposg);
  final_k<<<1, 1024, 0, stream>>>(totg, tposg, pl, sl, ghist, (float*)d_out);
}